// Round 3
// baseline (3333.094 us; speedup 1.0000x reference)
//
#include <hip/hip_runtime.h>
#include <hip/hip_bf16.h>

#define BB 8
#define HH 96
#define WW2 96
#define DIM 384
#define HEADS 12
#define HD 32
#define WS 12
#define DISP 6
#define NWH 8
#define NWW 8
#define NW 64
#define TPW 144           // tokens per window (12*12)
#define INNER 384         // HEADS*HD
#define NQKV 1152         // 3*INNER
#define MTOK (BB*NW*TPW)  // 73728 tokens total
#define SCALE 0.17677669529663687f

typedef unsigned short ushort8_t __attribute__((ext_vector_type(8)));

__device__ __forceinline__ float us2f(unsigned short u) {
    union { unsigned int u32; float f; } c; c.u32 = ((unsigned int)u) << 16; return c.f;
}
__device__ __forceinline__ unsigned short f2us(float f) {
    union { float f; unsigned int u; } c; c.f = f;
    unsigned int u = c.u;
    u += 0x7FFFu + ((u >> 16) & 1u);   // round-to-nearest-even
    return (unsigned short)(u >> 16);
}

// Fused: per-(b,head,window) block computes q/k/v = xs_window @ wqkv_headslice,
// then masked softmax attention, writes ao (bf16) in windowed token order.
// Zero FLOP duplication: each head uses only its own 96 wqkv columns.
__global__ __launch_bounds__(256) void fused_attn(
    const float* __restrict__ x,
    const float* __restrict__ wqkv,
    const int* __restrict__ pix_map,
    const float* __restrict__ pos_emb,   // [23][23]
    const float* __restrict__ pix_emb,   // [2]
    unsigned short* __restrict__ ao)     // [MTOK][INNER] windowed, bf16
{
    __shared__ float qs[TPW][HD];        // scaled q
    __shared__ float ks[TPW][HD + 1];    // +1 pad: avoid same-bank serialization
    __shared__ float vs[TPW][HD];
    __shared__ float xw[TPW][33];        // K-chunk of x window (padded)
    __shared__ float wc[32][96];         // K-chunk of wqkv head slice
    __shared__ float sc[36][TPW];
    __shared__ float pos[23 * 23];
    __shared__ int   pmv[TPW];
    __shared__ int   rowoff[TPW];

    const int tid = threadIdx.x;
    const int w = blockIdx.x, h = blockIdx.y, b = blockIdx.z;
    const int nwy = w >> 3, nww = w & 7;
    const int tbase = (b * NW + w) * TPW;

    if (tid < TPW) {
        int ri = tid / WS, ci = tid - ri * WS;
        int ys = nwy * WS + ri, xs2 = nww * WS + ci;
        int yin = ys + DISP; if (yin >= HH) yin -= HH;
        int xin = xs2 + DISP; if (xin >= WW2) xin -= WW2;
        rowoff[tid] = ((b * HH + yin) * WW2 + xin) * DIM;     // shifted gather
        pmv[tid] = pix_map[(b * HH + ys) * WW2 + xs2];        // UNshifted (ref quirk)
    }
    for (int idx = tid; idx < 529; idx += 256) pos[idx] = pos_emb[idx];
    __syncthreads();

    // ---- Phase A: q/k/v = xwin(144x384) @ wslice(384x96), K-chunks of 32 ----
    const int ty = tid >> 4, tx = tid & 15;   // ty: 9-row group, tx: 6-col group
    float acc[9][6] = {};
    for (int k0 = 0; k0 < DIM; k0 += 32) {
        for (int idx = tid; idx < 1152; idx += 256) {         // 144 rows x 8 float4
            int r = idx >> 3, g = (idx & 7) << 2;
            float4 v4 = *(const float4*)(x + rowoff[r] + k0 + g);
            xw[r][g + 0] = v4.x; xw[r][g + 1] = v4.y;
            xw[r][g + 2] = v4.z; xw[r][g + 3] = v4.w;
        }
        for (int idx = tid; idx < 768; idx += 256) {          // 32k x 24 float4
            int kk = idx / 24, g4 = idx - kk * 24;            // g4 0..23
            int s = g4 >> 3, c4 = (g4 & 7) << 2;              // s=q/k/v, c4 0..28
            float4 v4 = *(const float4*)(wqkv + (k0 + kk) * NQKV + s * INNER + h * HD + c4);
            float* dst = &wc[kk][s * 32 + c4];
            dst[0] = v4.x; dst[1] = v4.y; dst[2] = v4.z; dst[3] = v4.w;
        }
        __syncthreads();
        for (int kk = 0; kk < 32; kk++) {
            float av[9], bv[6];
            #pragma unroll
            for (int i = 0; i < 9; i++) av[i] = xw[ty * 9 + i][kk];
            #pragma unroll
            for (int j = 0; j < 6; j++) bv[j] = wc[kk][tx * 6 + j];
            #pragma unroll
            for (int i = 0; i < 9; i++)
                #pragma unroll
                for (int j = 0; j < 6; j++) acc[i][j] += av[i] * bv[j];
        }
        __syncthreads();
    }
    #pragma unroll
    for (int i = 0; i < 9; i++) {
        int r = ty * 9 + i;
        #pragma unroll
        for (int j = 0; j < 6; j++) {
            int c = tx * 6 + j;          // 0..95
            int s = c >> 5, cc = c & 31;
            float v = acc[i][j];
            if (s == 0)      qs[r][cc] = v * SCALE;
            else if (s == 1) ks[r][cc] = v;
            else             vs[r][cc] = v;
        }
    }
    __syncthreads();

    // ---- Phase B: masked attention ----
    const float pe0 = pix_emb[0], pe1 = pix_emb[1];
    const bool ul = (nwy == NWH - 1), lr = (nww == NWW - 1);
    const int wave = tid >> 6, lane = tid & 63;

    for (int r0 = 0; r0 < TPW; r0 += 36) {
        // scores: 9 groups of 4 rows x 144 cols
        for (int idx = tid; idx < 9 * TPW; idx += 256) {
            int ig = idx / TPW, j = idx - ig * TPW;
            int i0 = r0 + ig * 4;
            float a0 = 0.f, a1 = 0.f, a2 = 0.f, a3 = 0.f;
            #pragma unroll
            for (int d = 0; d < HD; d++) {
                float kv = ks[j][d];
                a0 += qs[i0 + 0][d] * kv;
                a1 += qs[i0 + 1][d] * kv;
                a2 += qs[i0 + 2][d] * kv;
                a3 += qs[i0 + 3][d] * kv;
            }
            int rj = j / WS, cj = j - rj * WS;
            int pj = pmv[j];
            float accs[4] = {a0, a1, a2, a3};
            #pragma unroll
            for (int r = 0; r < 4; r++) {
                int i = i0 + r;
                int ri = i / WS, ci = i - ri * WS;
                float a = accs[r];
                a += pos[(rj - ri + 11) * 23 + (cj - ci + 11)];
                a += (pmv[i] * pj) ? pe1 : pe0;
                if (ul && ((ri >= 6) != (rj >= 6))) a -= 1e30f;
                if (lr && ((ci >= 6) != (cj >= 6))) a -= 1e30f;
                sc[i - r0][j] = a;
            }
        }
        __syncthreads();
        // softmax: each wave owns rows wave, wave+4, ...
        for (int il = wave; il < 36; il += 4) {
            float s1 = sc[il][lane];
            float s2 = sc[il][lane + 64];
            float s3 = (lane < 16) ? sc[il][lane + 128] : -3e38f;
            float mx = fmaxf(s1, fmaxf(s2, s3));
            #pragma unroll
            for (int off = 32; off; off >>= 1) mx = fmaxf(mx, __shfl_xor(mx, off));
            float e1 = __expf(s1 - mx);
            float e2 = __expf(s2 - mx);
            float e3 = (lane < 16) ? __expf(s3 - mx) : 0.f;
            float sum = e1 + e2 + e3;
            #pragma unroll
            for (int off = 32; off; off >>= 1) sum += __shfl_xor(sum, off);
            float inv = 1.0f / sum;
            sc[il][lane] = e1 * inv;
            sc[il][lane + 64] = e2 * inv;
            if (lane < 16) sc[il][lane + 128] = e3 * inv;
        }
        __syncthreads();
        // PV: rows g, g+8, g+16, g+24 (+g+32 if g<4), col d
        {
            int d = tid & 31, g = tid >> 5;
            int i4 = (g < 4) ? (g + 32) : g;  // valid row either way
            float o0 = 0.f, o1 = 0.f, o2 = 0.f, o3 = 0.f, o4 = 0.f;
            #pragma unroll 4
            for (int j = 0; j < TPW; j++) {
                float vv = vs[j][d];
                o0 += sc[g][j] * vv;
                o1 += sc[g + 8][j] * vv;
                o2 += sc[g + 16][j] * vv;
                o3 += sc[g + 24][j] * vv;
                o4 += sc[i4][j] * vv;
            }
            int col = h * HD + d;
            ao[(size_t)(tbase + r0 + g) * INNER + col] = f2us(o0);
            ao[(size_t)(tbase + r0 + g + 8) * INNER + col] = f2us(o1);
            ao[(size_t)(tbase + r0 + g + 16) * INNER + col] = f2us(o2);
            ao[(size_t)(tbase + r0 + g + 24) * INNER + col] = f2us(o3);
            if (g < 4)
                ao[(size_t)(tbase + r0 + g + 32) * INNER + col] = f2us(o4);
        }
        __syncthreads();
    }
}

#define TM 64
#define TN 64
#define TK 32

// K3: out = ao @ w_out + b_out, scattered through inverse window + roll(+6,+6)
__global__ __launch_bounds__(256) void proj_gemm(
    const unsigned short* __restrict__ ao,   // bf16
    const float* __restrict__ wout,
    const float* __restrict__ bout,
    float* __restrict__ out)
{
    __shared__ float As[TK][TM];
    __shared__ float Bs[TK][TN];
    __shared__ int rowoff[TM];
    const int tid = threadIdx.x;
    const int n0 = blockIdx.x * TN;
    const int m0 = blockIdx.y * TM;
    if (tid < TM) {
        int t = m0 + tid;
        int b = t / (NW * TPW);
        int r = t - b * (NW * TPW);
        int w = r / TPW;
        int i = r - w * TPW;
        int nwy = w >> 3, nww = w & 7;
        int ri = i / WS, ci = i - ri * WS;
        int ys = nwy * WS + ri, xs = nww * WS + ci;
        int yo = ys + DISP; if (yo >= HH) yo -= HH;
        int xo = xs + DISP; if (xo >= WW2) xo -= WW2;
        rowoff[tid] = ((b * HH + yo) * WW2 + xo) * DIM;
    }
    __syncthreads();
    const int tx = tid & 15, ty = tid >> 4;
    const int am = tid >> 2, ad = (tid & 3) << 3;
    const int bk = tid >> 3, bn = (tid & 7) << 3;
    float acc[4][4] = {};
    for (int k0 = 0; k0 < INNER; k0 += TK) {
        ushort8_t a8 = *(const ushort8_t*)(ao + (size_t)(m0 + am) * INNER + k0 + ad);
        float4 b0 = *(const float4*)(wout + (k0 + bk) * DIM + n0 + bn);
        float4 b1 = *(const float4*)(wout + (k0 + bk) * DIM + n0 + bn + 4);
        #pragma unroll
        for (int j = 0; j < 8; j++) As[ad + j][am] = us2f(a8[j]);
        *(float4*)&Bs[bk][bn]     = b0;
        *(float4*)&Bs[bk][bn + 4] = b1;
        __syncthreads();
        #pragma unroll
        for (int kk = 0; kk < TK; kk++) {
            float4 a = *(const float4*)&As[kk][ty * 4];
            float4 b = *(const float4*)&Bs[kk][tx * 4];
            float av[4] = {a.x, a.y, a.z, a.w};
            float bv[4] = {b.x, b.y, b.z, b.w};
            #pragma unroll
            for (int ii = 0; ii < 4; ii++)
                #pragma unroll
                for (int jj = 0; jj < 4; jj++)
                    acc[ii][jj] += av[ii] * bv[jj];
        }
        __syncthreads();
    }
    float4 bo = *(const float4*)(bout + n0 + tx * 4);
    #pragma unroll
    for (int ii = 0; ii < 4; ii++) {
        float4 r;
        r.x = acc[ii][0] + bo.x;
        r.y = acc[ii][1] + bo.y;
        r.z = acc[ii][2] + bo.z;
        r.w = acc[ii][3] + bo.w;
        *(float4*)(out + (size_t)rowoff[ty * 4 + ii] + n0 + tx * 4) = r;
    }
}

extern "C" void kernel_launch(void* const* d_in, const int* in_sizes, int n_in,
                              void* d_out, int out_size, void* d_ws, size_t ws_size,
                              hipStream_t stream) {
    const float* x       = (const float*)d_in[0];
    const int*   pix_map = (const int*)d_in[1];
    const float* wqkv    = (const float*)d_in[2];
    const float* pos_emb = (const float*)d_in[3];
    const float* pix_emb = (const float*)d_in[4];
    const float* wout    = (const float*)d_in[5];
    const float* bout    = (const float*)d_in[6];
    float* out = (float*)d_out;

    unsigned short* ao = (unsigned short*)d_ws;   // MTOK x 384 bf16 = 56.6 MB

    dim3 g2(NW, HEADS, BB);
    fused_attn<<<g2, 256, 0, stream>>>(x, wqkv, pix_map, pos_emb, pix_emb, ao);

    dim3 g3(DIM / TN, MTOK / TM);
    proj_gemm<<<g3, 256, 0, stream>>>(ao, wout, bout, out);
}

// Round 4
// 1531.696 us; speedup vs baseline: 2.1761x; 2.1761x over previous
//
#include <hip/hip_runtime.h>
#include <hip/hip_bf16.h>

#define BB 8
#define HH 96
#define WW2 96
#define DIM 384
#define HEADS 12
#define HD 32
#define WS 12
#define DISP 6
#define NWH 8
#define NWW 8
#define NW 64
#define TPW 144           // tokens per window (12*12)
#define INNER 384         // HEADS*HD
#define NQKV 1152         // 3*INNER
#define MTOK (BB*NW*TPW)  // 73728 tokens total
#define SCALE 0.17677669529663687f

typedef short short8_t __attribute__((ext_vector_type(8)));
typedef float float4_t __attribute__((ext_vector_type(4)));
typedef unsigned short ushort8_t __attribute__((ext_vector_type(8)));

__device__ __forceinline__ float us2f(unsigned short u) {
    union { unsigned int u32; float f; } c; c.u32 = ((unsigned int)u) << 16; return c.f;
}
__device__ __forceinline__ unsigned short f2us(float f) {
    union { float f; unsigned int u; } c; c.f = f;
    unsigned int u = c.u;
    u += 0x7FFFu + ((u >> 16) & 1u);   // round-to-nearest-even
    return (unsigned short)(u >> 16);
}

// tiny: wqkvT[n][k] = bf16(wqkv[k][n])
__global__ __launch_bounds__(256) void cast_wqkvT(
    const float* __restrict__ wqkv, unsigned short* __restrict__ wqkvT)
{
    int idx = blockIdx.x * 256 + threadIdx.x;
    if (idx >= NQKV * DIM) return;
    int n = idx / DIM, k = idx - n * DIM;
    wqkvT[idx] = f2us(wqkv[k * NQKV + n]);
}

// Fused per-(b,head,window): Phase A = MFMA GEMM q|k|v(144x96) = xwin(144x384) @ wT,
// Phase B = masked softmax attention (VALU, fp32 LDS).
__global__ __launch_bounds__(256, 2) void fused_attn(
    const float* __restrict__ x,
    const unsigned short* __restrict__ wqkvT,   // [1152][384] bf16
    const int* __restrict__ pix_map,
    const float* __restrict__ pos_emb,          // [23][23]
    const float* __restrict__ pix_emb,          // [2]
    unsigned short* __restrict__ ao)            // [MTOK][INNER] windowed, bf16
{
    __shared__ float qs[TPW][HD + 1];   // scaled q
    __shared__ float ks[TPW][HD + 1];
    __shared__ float vs[TPW][HD + 1];
    __align__(16) __shared__ char uni[36 * TPW * 4];  // staging (15360 B) / sc (20736 B)
    __shared__ float pos[23 * 23];
    __shared__ int   pmv[TPW];
    __shared__ int   rowoff[TPW];

    unsigned short* xw  = (unsigned short*)uni;            // [144][32] bf16
    unsigned short* wcT = (unsigned short*)(uni + 9216);   // [96][32] bf16
    float (*sc)[TPW] = (float(*)[TPW])uni;                 // [36][144] fp32

    const int tid = threadIdx.x;
    const int w = blockIdx.x, h = blockIdx.y, b = blockIdx.z;
    const int nwy = w >> 3, nww = w & 7;
    const int tbase = (b * NW + w) * TPW;

    if (tid < TPW) {
        int ri = tid / WS, ci = tid - ri * WS;
        int ys = nwy * WS + ri, xs2 = nww * WS + ci;
        int yin = ys + DISP; if (yin >= HH) yin -= HH;
        int xin = xs2 + DISP; if (xin >= WW2) xin -= WW2;
        rowoff[tid] = ((b * HH + yin) * WW2 + xin) * DIM;     // shifted gather
        pmv[tid] = pix_map[(b * HH + ys) * WW2 + xs2];        // UNshifted (ref quirk)
    }
    for (int idx = tid; idx < 529; idx += 256) pos[idx] = pos_emb[idx];
    __syncthreads();

    // ---- Phase A: MFMA GEMM, 9x6 grid of 16x16x32 tiles, waves 2x2 ----
    const int wave = tid >> 6, lane = tid & 63;
    const int quad = lane >> 4, l16 = lane & 15;
    const int mw = wave >> 1, nw = wave & 1;
    const int nmt = mw ? 4 : 5;                 // m-tiles: 0..4 / 5..8
    const int mbase = mw * 5, nbase = nw * 3;

    float4_t acc[5][3];
    #pragma unroll
    for (int i = 0; i < 5; i++)
        #pragma unroll
        for (int j = 0; j < 3; j++) acc[i][j] = (float4_t){0.f, 0.f, 0.f, 0.f};

    for (int k0 = 0; k0 < DIM; k0 += 32) {
        for (int idx = tid; idx < 576; idx += 256) {          // xw: 144 rows x 4 chunks
            int r = idx >> 2, qr = idx & 3;
            const float* src = x + rowoff[r] + k0 + qr * 8;
            float4 a = *(const float4*)src;
            float4 c = *(const float4*)(src + 4);
            ushort8_t u;
            u[0] = f2us(a.x); u[1] = f2us(a.y); u[2] = f2us(a.z); u[3] = f2us(a.w);
            u[4] = f2us(c.x); u[5] = f2us(c.y); u[6] = f2us(c.z); u[7] = f2us(c.w);
            *(ushort8_t*)(xw + r * 32 + qr * 8) = u;
        }
        for (int idx = tid; idx < 384; idx += 256) {          // wcT: 96 rows x 4 chunks
            int r = idx >> 2, c = (idx & 3) << 3;
            int s = r >> 5, nn = r & 31;
            int gn = s * INNER + h * HD + nn;
            *(ushort8_t*)(wcT + r * 32 + c) =
                *(const ushort8_t*)(wqkvT + gn * DIM + k0 + c);
        }
        __syncthreads();
        short8_t afr[5], bfr[3];
        #pragma unroll
        for (int j = 0; j < 3; j++)
            bfr[j] = *(short8_t*)(wcT + ((nbase + j) * 16 + l16) * 32 + quad * 8);
        #pragma unroll
        for (int i = 0; i < 5; i++)
            if (i < nmt)
                afr[i] = *(short8_t*)(xw + ((mbase + i) * 16 + l16) * 32 + quad * 8);
        #pragma unroll
        for (int i = 0; i < 5; i++)
            if (i < nmt)
                #pragma unroll
                for (int j = 0; j < 3; j++)
                    acc[i][j] = __builtin_amdgcn_mfma_f32_16x16x32_bf16(
                        afr[i], bfr[j], acc[i][j], 0, 0, 0);
        __syncthreads();
    }
    // C writeback: D col = lane&15, row = quad*4 + reg (m89-verified layout)
    #pragma unroll
    for (int i = 0; i < 5; i++)
        if (i < nmt) {
            int tm = mbase + i;
            #pragma unroll
            for (int j = 0; j < 3; j++) {
                int tn = nbase + j;
                int s = tn >> 1;                    // 0=q, 1=k, 2=v (tile-uniform)
                int cc = ((tn & 1) << 4) | l16;
                float* dst = (s == 0) ? &qs[0][0] : (s == 1) ? &ks[0][0] : &vs[0][0];
                float mul = (s == 0) ? SCALE : 1.0f;
                #pragma unroll
                for (int r = 0; r < 4; r++) {
                    int m = tm * 16 + quad * 4 + r;
                    dst[m * (HD + 1) + cc] = acc[i][j][r] * mul;
                }
            }
        }
    __syncthreads();

    // ---- Phase B: masked attention (unchanged numeric path) ----
    const float pe0 = pix_emb[0], pe1 = pix_emb[1];
    const bool ul = (nwy == NWH - 1), lr = (nww == NWW - 1);

    for (int r0 = 0; r0 < TPW; r0 += 36) {
        for (int idx = tid; idx < 9 * TPW; idx += 256) {
            int ig = idx / TPW, j = idx - ig * TPW;
            int i0 = r0 + ig * 4;
            float a0 = 0.f, a1 = 0.f, a2 = 0.f, a3 = 0.f;
            #pragma unroll
            for (int d = 0; d < HD; d++) {
                float kv = ks[j][d];
                a0 += qs[i0 + 0][d] * kv;
                a1 += qs[i0 + 1][d] * kv;
                a2 += qs[i0 + 2][d] * kv;
                a3 += qs[i0 + 3][d] * kv;
            }
            int rj = j / WS, cj = j - rj * WS;
            int pj = pmv[j];
            float accs[4] = {a0, a1, a2, a3};
            #pragma unroll
            for (int r = 0; r < 4; r++) {
                int i = i0 + r;
                int ri = i / WS, ci = i - ri * WS;
                float a = accs[r];
                a += pos[(rj - ri + 11) * 23 + (cj - ci + 11)];
                a += (pmv[i] * pj) ? pe1 : pe0;
                if (ul && ((ri >= 6) != (rj >= 6))) a -= 1e30f;
                if (lr && ((ci >= 6) != (cj >= 6))) a -= 1e30f;
                sc[i - r0][j] = a;
            }
        }
        __syncthreads();
        for (int il = wave; il < 36; il += 4) {
            float s1 = sc[il][lane];
            float s2 = sc[il][lane + 64];
            float s3 = (lane < 16) ? sc[il][lane + 128] : -3e38f;
            float mx = fmaxf(s1, fmaxf(s2, s3));
            #pragma unroll
            for (int off = 32; off; off >>= 1) mx = fmaxf(mx, __shfl_xor(mx, off));
            float e1 = __expf(s1 - mx);
            float e2 = __expf(s2 - mx);
            float e3 = (lane < 16) ? __expf(s3 - mx) : 0.f;
            float sum = e1 + e2 + e3;
            #pragma unroll
            for (int off = 32; off; off >>= 1) sum += __shfl_xor(sum, off);
            float inv = 1.0f / sum;
            sc[il][lane] = e1 * inv;
            sc[il][lane + 64] = e2 * inv;
            if (lane < 16) sc[il][lane + 128] = e3 * inv;
        }
        __syncthreads();
        {
            int d = tid & 31, g = tid >> 5;
            int i4 = (g < 4) ? (g + 32) : g;
            float o0 = 0.f, o1 = 0.f, o2 = 0.f, o3 = 0.f, o4 = 0.f;
            #pragma unroll 4
            for (int j = 0; j < TPW; j++) {
                float vv = vs[j][d];
                o0 += sc[g][j] * vv;
                o1 += sc[g + 8][j] * vv;
                o2 += sc[g + 16][j] * vv;
                o3 += sc[g + 24][j] * vv;
                o4 += sc[i4][j] * vv;
            }
            int col = h * HD + d;
            ao[(size_t)(tbase + r0 + g) * INNER + col] = f2us(o0);
            ao[(size_t)(tbase + r0 + g + 8) * INNER + col] = f2us(o1);
            ao[(size_t)(tbase + r0 + g + 16) * INNER + col] = f2us(o2);
            ao[(size_t)(tbase + r0 + g + 24) * INNER + col] = f2us(o3);
            if (g < 4)
                ao[(size_t)(tbase + r0 + g + 32) * INNER + col] = f2us(o4);
        }
        __syncthreads();
    }
}

#define TM 64
#define TN 64
#define TK 32

// K3: out = ao @ w_out + b_out, scattered through inverse window + roll(+6,+6)
__global__ __launch_bounds__(256) void proj_gemm(
    const unsigned short* __restrict__ ao,   // bf16
    const float* __restrict__ wout,
    const float* __restrict__ bout,
    float* __restrict__ out)
{
    __shared__ float As[TK][TM];
    __shared__ float Bs[TK][TN];
    __shared__ int rowoff[TM];
    const int tid = threadIdx.x;
    const int n0 = blockIdx.x * TN;
    const int m0 = blockIdx.y * TM;
    if (tid < TM) {
        int t = m0 + tid;
        int b = t / (NW * TPW);
        int r = t - b * (NW * TPW);
        int w = r / TPW;
        int i = r - w * TPW;
        int nwy = w >> 3, nww = w & 7;
        int ri = i / WS, ci = i - ri * WS;
        int ys = nwy * WS + ri, xs = nww * WS + ci;
        int yo = ys + DISP; if (yo >= HH) yo -= HH;
        int xo = xs + DISP; if (xo >= WW2) xo -= WW2;
        rowoff[tid] = ((b * HH + yo) * WW2 + xo) * DIM;
    }
    __syncthreads();
    const int tx = tid & 15, ty = tid >> 4;
    const int am = tid >> 2, ad = (tid & 3) << 3;
    const int bk = tid >> 3, bn = (tid & 7) << 3;
    float acc[4][4] = {};
    for (int k0 = 0; k0 < INNER; k0 += TK) {
        ushort8_t a8 = *(const ushort8_t*)(ao + (size_t)(m0 + am) * INNER + k0 + ad);
        float4 b0 = *(const float4*)(wout + (k0 + bk) * DIM + n0 + bn);
        float4 b1 = *(const float4*)(wout + (k0 + bk) * DIM + n0 + bn + 4);
        #pragma unroll
        for (int j = 0; j < 8; j++) As[ad + j][am] = us2f(a8[j]);
        *(float4*)&Bs[bk][bn]     = b0;
        *(float4*)&Bs[bk][bn + 4] = b1;
        __syncthreads();
        #pragma unroll
        for (int kk = 0; kk < TK; kk++) {
            float4 a = *(const float4*)&As[kk][ty * 4];
            float4 b = *(const float4*)&Bs[kk][tx * 4];
            float av[4] = {a.x, a.y, a.z, a.w};
            float bv[4] = {b.x, b.y, b.z, b.w};
            #pragma unroll
            for (int ii = 0; ii < 4; ii++)
                #pragma unroll
                for (int jj = 0; jj < 4; jj++)
                    acc[ii][jj] += av[ii] * bv[jj];
        }
        __syncthreads();
    }
    float4 bo = *(const float4*)(bout + n0 + tx * 4);
    #pragma unroll
    for (int ii = 0; ii < 4; ii++) {
        float4 r;
        r.x = acc[ii][0] + bo.x;
        r.y = acc[ii][1] + bo.y;
        r.z = acc[ii][2] + bo.z;
        r.w = acc[ii][3] + bo.w;
        *(float4*)(out + (size_t)rowoff[ty * 4 + ii] + n0 + tx * 4) = r;
    }
}

extern "C" void kernel_launch(void* const* d_in, const int* in_sizes, int n_in,
                              void* d_out, int out_size, void* d_ws, size_t ws_size,
                              hipStream_t stream) {
    const float* x       = (const float*)d_in[0];
    const int*   pix_map = (const int*)d_in[1];
    const float* wqkv    = (const float*)d_in[2];
    const float* pos_emb = (const float*)d_in[3];
    const float* pix_emb = (const float*)d_in[4];
    const float* wout    = (const float*)d_in[5];
    const float* bout    = (const float*)d_in[6];
    float* out = (float*)d_out;

    unsigned short* ao     = (unsigned short*)d_ws;          // MTOK x 384 bf16
    unsigned short* wqkvT  = ao + (size_t)MTOK * INNER;      // 1152 x 384 bf16

    cast_wqkvT<<<(NQKV * DIM + 255) / 256, 256, 0, stream>>>(wqkv, wqkvT);

    dim3 g2(NW, HEADS, BB);
    fused_attn<<<g2, 256, 0, stream>>>(x, wqkvT, pix_map, pos_emb, pix_emb, ao);

    dim3 g3(DIM / TN, MTOK / TM);
    proj_gemm<<<g3, 256, 0, stream>>>(ao, wout, bout, out);
}